// Round 6
// baseline (176.665 us; speedup 1.0000x reference)
//
#include <hip/hip_runtime.h>
#include <stdint.h>

#define D_DIM   512
#define BM      128
#define THREADS 512            // 8 waves
#define NBLOCKS 1024           // 131072 / 128, non-persistent, ~2 blocks/CU

typedef __attribute__((ext_vector_type(8))) __bf16 bf16x8;
typedef __attribute__((ext_vector_type(4))) float  f32x4;

__device__ __forceinline__ unsigned short f32_to_bf16_rne(float f) {
    uint32_t u = __builtin_bit_cast(uint32_t, f);
    u += 0x7FFFu + ((u >> 16) & 1u);
    return (unsigned short)(u >> 16);
}
__device__ __forceinline__ ushort4 cvt_f4_bf4(float4 v) {
    ushort4 h;
    h.x = f32_to_bf16_rne(v.x); h.y = f32_to_bf16_rne(v.y);
    h.z = f32_to_bf16_rne(v.z); h.w = f32_to_bf16_rne(v.w);
    return h;
}

// Repack L (fp32 row-major [K=512][N=512]) into bf16 fragment order:
// flat ushort idx = ((ks*32 + ntg)*64 + lane)*8 + e  holds L[k][n],
//   n = ntg*16 + (lane&15),  k = ks*32 + (lane>>4)*8 + e.
__global__ void prep_lt(const float* __restrict__ L, unsigned short* __restrict__ Ltf) {
    int o = blockIdx.x * 256 + threadIdx.x;
    #pragma unroll
    for (int i = 0; i < 4; ++i) {
        int idx  = o + i * 65536;
        int e    = idx & 7;
        int l    = (idx >> 3) & 63;
        int tile = idx >> 9;
        int ntg  = tile & 31;
        int ks   = tile >> 5;
        int n    = ntg * 16 + (l & 15);
        int k    = ks * 32 + (l >> 4) * 8 + e;
        Ltf[idx] = f32_to_bf16_rne(L[k * 512 + n]);
    }
}

__global__ __launch_bounds__(THREADS, 1)
void psd_main(const float* __restrict__ x, const unsigned short* __restrict__ Ltf,
              const float* __restrict__ b, const float* __restrict__ c,
              float* __restrict__ out) {
    __shared__ __align__(16) unsigned short As[2][BM * 128];  // 2 x 32 KiB K-quarter ring
    __shared__ float wpart[8][BM];
    __shared__ float bpart[BM];

    const int t    = threadIdx.x;
    const int w    = t >> 6;          // wave 0..7, owns n-cols [w*64, w*64+64)
    const int lane = t & 63;
    const int g    = lane >> 4;
    const int ln   = lane & 15;
    const int swz  = (ln & 7) << 4;
    const int tb5  = t >> 5;          // 0..15 (row sub-slot)
    const int c4   = t & 31;          // float4-column within a quarter

    char* AsB = (char*)As;
    const float4* xt4 = (const float4*)x + (size_t)blockIdx.x * BM * (D_DIM / 4);
    const float4* b4  = (const float4*)b;
    const float   c0  = c[0];
    const unsigned short* LtW = Ltf + (size_t)w * 2048 + (size_t)lane * 8;

    f32x4 acc[8][4];
    #pragma unroll
    for (int m = 0; m < 8; ++m)
        #pragma unroll
        for (int nt = 0; nt < 4; ++nt)
            acc[m][nt] = (f32x4){0.f, 0.f, 0.f, 0.f};
    float bacc[8] = {0.f, 0.f, 0.f, 0.f, 0.f, 0.f, 0.f, 0.f};

    // persistent B double-buffer (L2-resident fragment-order L)
    bf16x8 bcur[4];
    #pragma unroll
    for (int nt = 0; nt < 4; ++nt)
        bcur[nt] = *(const bf16x8*)(LtW + nt * 512);

    // ---- prologue: stage quarter 0 into slot 0, fold x.b partial ----
    {
        float4 bb = b4[c4];
        float4 v[8];
        #pragma unroll
        for (int j = 0; j < 8; ++j)
            v[j] = xt4[(size_t)(j * 16 + tb5) * 128 + c4];
        #pragma unroll
        for (int j = 0; j < 8; ++j) {
            bacc[j] += v[j].x * bb.x + v[j].y * bb.y + v[j].z * bb.z + v[j].w * bb.w;
            int row = j * 16 + tb5;
            *(ushort4*)(AsB + row * 256 + ((c4 * 8) ^ ((row & 7) << 4))) = cvt_f4_bf4(v[j]);
        }
    }
    __syncthreads();

#define COMPUTE_KS(Q, KL)                                                               \
    {                                                                                   \
        const int ksn = ((Q) * 4 + (KL) + 1) & 15;                                      \
        bf16x8 bnxt[4];                                                                 \
        _Pragma("unroll")                                                               \
        for (int nt = 0; nt < 4; ++nt)                                                  \
            bnxt[nt] = *(const bf16x8*)(LtW + ksn * 16384 + nt * 512);                  \
        const int colb = (((KL) * 64 + g * 16) ^ swz);                                  \
        bf16x8 a[4];                                                                    \
        _Pragma("unroll")                                                               \
        for (int m = 0; m < 4; ++m)                                                     \
            a[m] = *(const bf16x8*)(rbase + (m * 16 + ln) * 256 + colb);                \
        _Pragma("unroll")                                                               \
        for (int nt = 0; nt < 4; ++nt)                                                  \
            _Pragma("unroll")                                                           \
            for (int m = 0; m < 4; ++m)                                                 \
                acc[m][nt] = __builtin_amdgcn_mfma_f32_16x16x32_bf16(a[m], bcur[nt], acc[m][nt], 0, 0, 0); \
        _Pragma("unroll")                                                               \
        for (int m = 0; m < 4; ++m)                                                     \
            a[m] = *(const bf16x8*)(rbase + ((m + 4) * 16 + ln) * 256 + colb);          \
        _Pragma("unroll")                                                               \
        for (int nt = 0; nt < 4; ++nt)                                                  \
            _Pragma("unroll")                                                           \
            for (int m = 0; m < 4; ++m)                                                 \
                acc[m + 4][nt] = __builtin_amdgcn_mfma_f32_16x16x32_bf16(a[m], bcur[nt], acc[m + 4][nt], 0, 0, 0); \
        _Pragma("unroll")                                                               \
        for (int nt = 0; nt < 4; ++nt) bcur[nt] = bnxt[nt];                             \
    }

#define WRITE_BATCH(VV, J0)                                                             \
    {                                                                                   \
        _Pragma("unroll")                                                               \
        for (int jj = 0; jj < 4; ++jj) {                                                \
            const int j = (J0) + jj;                                                    \
            bacc[j] += (VV)[jj].x * bb.x + (VV)[jj].y * bb.y                            \
                     + (VV)[jj].z * bb.z + (VV)[jj].w * bb.w;                           \
            const int row = j * 16 + tb5;                                               \
            *(ushort4*)(wbase + row * 256 + ((c4 * 8) ^ ((row & 7) << 4))) = cvt_f4_bf4((VV)[jj]); \
        }                                                                               \
    }

    #pragma unroll
    for (int q = 0; q < 4; ++q) {
        char* rbase = AsB + (q & 1) * 32768;
        char* wbase = AsB + ((q + 1) & 1) * 32768;
        const bool has_next = (q < 3);

        float4 bb = {0.f, 0.f, 0.f, 0.f};
        float4 va[4];
        if (has_next) {
            bb = b4[(q + 1) * 32 + c4];
            #pragma unroll
            for (int j = 0; j < 4; ++j)
                va[j] = xt4[(size_t)(j * 16 + tb5) * 128 + (q + 1) * 32 + c4];
        }

        COMPUTE_KS(q, 0)
        COMPUTE_KS(q, 1)

        if (has_next) WRITE_BATCH(va, 0)

        float4 vb[4];
        if (has_next) {
            #pragma unroll
            for (int j = 0; j < 4; ++j)
                vb[j] = xt4[(size_t)((j + 4) * 16 + tb5) * 128 + (q + 1) * 32 + c4];
        }

        COMPUTE_KS(q, 2)
        COMPUTE_KS(q, 3)

        if (has_next) WRITE_BATCH(vb, 4)

        __syncthreads();
    }
#undef COMPUTE_KS
#undef WRITE_BATCH

    // ---- rowsum of squares; C/D: col=lane&15, row=4*(lane>>4)+reg ----
    #pragma unroll
    for (int m = 0; m < 8; ++m)
        #pragma unroll
        for (int r = 0; r < 4; ++r) {
            float s = 0.f;
            #pragma unroll
            for (int nt = 0; nt < 4; ++nt) { float vv = acc[m][nt][r]; s += vv * vv; }
            s += __shfl_xor(s, 1);  s += __shfl_xor(s, 2);
            s += __shfl_xor(s, 4);  s += __shfl_xor(s, 8);
            if (ln == 0) wpart[w][m * 16 + g * 4 + r] = s;
        }

    // ---- x.b partials: reduce across the 32 threads sharing tb5 ----
    #pragma unroll
    for (int j = 0; j < 8; ++j) {
        float s = bacc[j];
        s += __shfl_xor(s, 1);  s += __shfl_xor(s, 2);
        s += __shfl_xor(s, 4);  s += __shfl_xor(s, 8);
        s += __shfl_xor(s, 16);
        if ((lane & 31) == 0) bpart[j * 16 + tb5] = s;
    }
    __syncthreads();

    if (t < BM) {
        float y = c0 + bpart[t];
        #pragma unroll
        for (int ww = 0; ww < 8; ++ww) y += wpart[ww][t];
        out[(size_t)blockIdx.x * BM + t] = y;
    }
}

extern "C" void kernel_launch(void* const* d_in, const int* in_sizes, int n_in,
                              void* d_out, int out_size, void* d_ws, size_t ws_size,
                              hipStream_t stream) {
    const float* x = (const float*)d_in[0];
    const float* L = (const float*)d_in[1];
    const float* b = (const float*)d_in[2];
    const float* c = (const float*)d_in[3];
    float* out = (float*)d_out;
    unsigned short* Ltf = (unsigned short*)d_ws;   // 512 KiB

    prep_lt<<<256, 256, 0, stream>>>(L, Ltf);
    psd_main<<<NBLOCKS, THREADS, 0, stream>>>(x, Ltf, b, c, out);
}

// Round 7
// 97.263 us; speedup vs baseline: 1.8164x; 1.8164x over previous
//
#include <hip/hip_runtime.h>
#include <stdint.h>

#define D_DIM   512
#define BM      64
#define THREADS 256            // 4 waves; each wave owns 128 N-cols (nt=8)
#define NBLOCKS 2048           // 131072 / 64

typedef __attribute__((ext_vector_type(8))) __bf16 bf16x8;
typedef __attribute__((ext_vector_type(4))) float  f32x4;

__device__ __forceinline__ unsigned short f32_to_bf16_rne(float f) {
    uint32_t u = __builtin_bit_cast(uint32_t, f);
    u += 0x7FFFu + ((u >> 16) & 1u);
    return (unsigned short)(u >> 16);
}

// Repack L (fp32 row-major [K=512][N=512]) into bf16 fragment order:
// flat ushort idx = ((ks*32 + ntg)*64 + lane)*8 + e  holds L[k][n],
//   n = ntg*16 + (lane&15),  k = ks*32 + (lane>>4)*8 + e.
__global__ void prep_lt(const float* __restrict__ L, unsigned short* __restrict__ Ltf) {
    int o = blockIdx.x * 256 + threadIdx.x;
    #pragma unroll
    for (int i = 0; i < 4; ++i) {
        int idx  = o + i * 65536;
        int e    = idx & 7;
        int l    = (idx >> 3) & 63;
        int tile = idx >> 9;
        int ntg  = tile & 31;
        int ks   = tile >> 5;
        int n    = ntg * 16 + (l & 15);
        int k    = ks * 32 + (l >> 4) * 8 + e;
        Ltf[idx] = f32_to_bf16_rne(L[k * 512 + n]);
    }
}

// b-tap fragment: B-operand tile whose column 0 is b (cols 1..15 zero).
// MFMA(A=x-frag, B=btap) puts x_row . b into C col 0 (lanes ln==0).
__global__ void prep_bt(const float* __restrict__ b, unsigned short* __restrict__ Btf) {
    int idx = blockIdx.x * 256 + threadIdx.x;   // 8192 items
    int e  = idx & 7;
    int l  = (idx >> 3) & 63;
    int ks = idx >> 9;
    int ln = l & 15, g = l >> 4;
    float v = (ln == 0) ? b[ks * 32 + g * 8 + e] : 0.f;
    Btf[idx] = f32_to_bf16_rne(v);
}

__global__ __launch_bounds__(THREADS, 2)
void psd_main(const float* __restrict__ x, const unsigned short* __restrict__ Ltf,
              const unsigned short* __restrict__ Btf,
              const float* __restrict__ c, float* __restrict__ out) {
    // two fp32 K-quarter slots [64 rows][128 cols], 16B-unit swizzled: unit s = c ^ (row&15)
    __shared__ __align__(16) float As[2][BM * 128];
    __shared__ float wpart[4][BM];

    const int t    = threadIdx.x;
    const int w    = t >> 6;
    const int lane = t & 63;
    const int g    = lane >> 4;
    const int ln   = lane & 15;
    const int lo   = lane & 31;
    const int hi   = lane >> 5;

    char* AsB = (char*)&As[0][0];
    const char* xB = (const char*)x + (size_t)blockIdx.x * (BM * 2048);

    const unsigned short* LtW = Ltf + (size_t)w * 4096 + (size_t)lane * 8;
    const unsigned short* BtL = Btf + (size_t)lane * 8;

    f32x4 acc[4][8];
    f32x4 accb[4];
    #pragma unroll
    for (int m = 0; m < 4; ++m) {
        accb[m] = (f32x4){0.f, 0.f, 0.f, 0.f};
        #pragma unroll
        for (int nt = 0; nt < 8; ++nt) acc[m][nt] = (f32x4){0.f, 0.f, 0.f, 0.f};
    }

    // Stage quarter Q (fp32 cols [Q*128, Q*128+128)) into slot Q&1.
    // Wave w covers rows w*16..w*16+15; instr j = rows w*16+2j, w*16+2j+1 (1 KB linear LDS).
    // Lane l fetches logical 16B-unit c = lo ^ (r&15) so LDS stored-unit lo holds c (involution).
#define STAGE(Q)                                                                         \
    {                                                                                    \
        char* ldsw = AsB + ((Q) & 1) * 32768 + w * 8192;                                 \
        _Pragma("unroll")                                                                \
        for (int j = 0; j < 8; ++j) {                                                    \
            int rr = j * 2 + hi;                         /* row & 15 */                  \
            const char* gsrc = xB + (size_t)(w * 16 + rr) * 2048 + (Q) * 512             \
                             + ((lo ^ rr) << 4);                                         \
            __builtin_amdgcn_global_load_lds(                                            \
                (const __attribute__((address_space(1))) void*)gsrc,                     \
                (__attribute__((address_space(3))) void*)(ldsw + j * 1024), 16, 0, 0);   \
        }                                                                                \
    }

    // Compute quarter Q from slot Q&1: 4 K-steps of 32, A built fp32->bf16 in regs.
#define COMPUTE(Q)                                                                       \
    {                                                                                    \
        const char* rb = AsB + ((Q) & 1) * 32768;                                        \
        _Pragma("unroll")                                                                \
        for (int kl = 0; kl < 4; ++kl) {                                                 \
            const int ks = (Q) * 4 + kl;                                                 \
            bf16x8 bfr[8];                                                               \
            _Pragma("unroll")                                                            \
            for (int nt = 0; nt < 8; ++nt)                                               \
                bfr[nt] = *(const bf16x8*)(LtW + (size_t)ks * 16384 + nt * 512);         \
            bf16x8 bt;                                                                   \
            if (w == 0) bt = *(const bf16x8*)(BtL + (size_t)ks * 512);                   \
            _Pragma("unroll")                                                            \
            for (int m = 0; m < 4; ++m) {                                                \
                const int row = m * 16 + ln;                                             \
                const int cb  = kl * 8 + g * 2;                                          \
                f32x4 f0 = *(const f32x4*)(rb + row * 512 + (((cb    ) ^ ln) << 4));     \
                f32x4 f1 = *(const f32x4*)(rb + row * 512 + (((cb + 1) ^ ln) << 4));     \
                bf16x8 a;                                                                \
                a[0] = (__bf16)f0[0]; a[1] = (__bf16)f0[1];                              \
                a[2] = (__bf16)f0[2]; a[3] = (__bf16)f0[3];                              \
                a[4] = (__bf16)f1[0]; a[5] = (__bf16)f1[1];                              \
                a[6] = (__bf16)f1[2]; a[7] = (__bf16)f1[3];                              \
                _Pragma("unroll")                                                        \
                for (int nt = 0; nt < 8; ++nt)                                           \
                    acc[m][nt] = __builtin_amdgcn_mfma_f32_16x16x32_bf16(a, bfr[nt], acc[m][nt], 0, 0, 0); \
                if (w == 0)                                                              \
                    accb[m] = __builtin_amdgcn_mfma_f32_16x16x32_bf16(a, bt, accb[m], 0, 0, 0); \
            }                                                                            \
        }                                                                                \
    }

    STAGE(0)
    __syncthreads();          // drains STAGE(0)'s own loads, joins waves
    STAGE(1)                  // flies under COMPUTE(0)
    COMPUTE(0)
    __syncthreads();          // drains STAGE(1); all waves done reading slot 0
    STAGE(2)
    COMPUTE(1)
    __syncthreads();
    STAGE(3)
    COMPUTE(2)
    __syncthreads();
    COMPUTE(3)

#undef STAGE
#undef COMPUTE

    // rowsum of squares; C/D layout: col = lane&15, row = 4*(lane>>4) + reg
    #pragma unroll
    for (int m = 0; m < 4; ++m) {
        #pragma unroll
        for (int r = 0; r < 4; ++r) {
            float s = 0.f;
            #pragma unroll
            for (int nt = 0; nt < 8; ++nt) { float vv = acc[m][nt][r]; s += vv * vv; }
            s += __shfl_xor(s, 1);
            s += __shfl_xor(s, 2);
            s += __shfl_xor(s, 4);
            s += __shfl_xor(s, 8);
            if (ln == 0) {
                if (w == 0) s += accb[m][r];   // x.b tap (col 0)
                wpart[w][m * 16 + g * 4 + r] = s;
            }
        }
    }
    __syncthreads();

    if (t < BM) {
        float y = c[0] + wpart[0][t] + wpart[1][t] + wpart[2][t] + wpart[3][t];
        out[(size_t)blockIdx.x * BM + t] = y;
    }
}

extern "C" void kernel_launch(void* const* d_in, const int* in_sizes, int n_in,
                              void* d_out, int out_size, void* d_ws, size_t ws_size,
                              hipStream_t stream) {
    const float* x = (const float*)d_in[0];
    const float* L = (const float*)d_in[1];
    const float* b = (const float*)d_in[2];
    const float* c = (const float*)d_in[3];
    float* out = (float*)d_out;
    unsigned short* Ltf = (unsigned short*)d_ws;     // 512 KiB
    unsigned short* Btf = Ltf + 262144;              // +16 KiB

    prep_lt<<<256, 256, 0, stream>>>(L, Ltf);
    prep_bt<<<32, 256, 0, stream>>>(b, Btf);
    psd_main<<<NBLOCKS, THREADS, 0, stream>>>(x, Ltf, Btf, c, out);
}